// Round 1
// 271.677 us; speedup vs baseline: 1.0206x; 1.0206x over previous
//
#include <hip/hip_runtime.h>
#include <hip/hip_bf16.h>

// Hopfield sparsemax attention, MI355X gfx950.
// B=1, L=S=2048, D_MODEL=1024, H=16, DK=64. Inputs fp32 (runtime-detected), output per flag.
//
// Round-10 (occupancy push on attn_fused):
//   - LDS 74752 -> 39680 B/block => 4 blocks/CU resident (was 2): sK tile 256->128 rows
//     (16 iters), candidate CAP 256->128.
//   - CAP=128 made safe by tighter threshold: track wave-local running top-2 (m1,m2);
//     thr = max(g1-1, (g1+m2-1)/2) is a valid lower bound on tau:
//       if m2 > tau: both in support -> (g1-tau)+(m2-tau) <= sum p = 1 -> tau >= (g1+m2-1)/2
//       else m2 <= tau and g1-1 <= tau -> (g1+m2-1)/2 <= tau.
//   - ballot-compacted candidate append: 1 atomicAdd per quad per col-group (<=16x fewer
//     LDS atomics), Michelot tail on 2 regs/lane.
//   Rest of pipeline unchanged (convert, transpose4, 64x64 gemm, final projection).

typedef __attribute__((ext_vector_type(8))) short short8;
typedef __attribute__((ext_vector_type(4))) float floatx4;

#define SRC_BF16 0
#define SRC_F32  1
#define SRC_RT   2
#define CAP 128

__device__ __forceinline__ short f2bf(float f) {
    __hip_bfloat16 h = __float2bfloat16(f);
    return *reinterpret_cast<const short*>(&h);
}
__device__ __forceinline__ unsigned short f2bfu(float f) {
    __hip_bfloat16 h = __float2bfloat16(f);
    return *reinterpret_cast<const unsigned short*>(&h);
}
__device__ __forceinline__ float bf2f(unsigned short u) {
    return __uint_as_float(((unsigned)u) << 16);
}
// monotone float->uint map (order-preserving for all finite floats)
__device__ __forceinline__ unsigned fmap(float f) {
    unsigned u = __float_as_uint(f);
    return (u & 0x80000000u) ? ~u : (u | 0x80000000u);
}
__device__ __forceinline__ float funmap(unsigned u) {
    return (u & 0x80000000u) ? __uint_as_float(u ^ 0x80000000u) : __uint_as_float(~u);
}

// Detect input dtype: decode first n shorts as bf16; fp32-read-as-bf16 almost surely
// yields |x|>1e10 / inf / NaN. One 64-thread block.
__global__ void detect_k(const short* __restrict__ q, int n, int* __restrict__ flag)
{
    const int tid = threadIdx.x;
    int bad = 0;
    for (int i = tid; i < n; i += 64) {
        float f = bf2f((unsigned short)q[i]);
        if (!(fabsf(f) < 1e10f)) bad = 1;
    }
    unsigned long long m = __ballot(bad != 0);
    if (tid == 0) *flag = (m != 0ULL) ? 1 : 0;
}

// Flat convert (fp32|bf16 per flag) -> bf16. z selects one of two sources.
__global__ __launch_bounds__(256)
void convert2_k(const void* __restrict__ s0, const void* __restrict__ s1,
                short* __restrict__ d0, short* __restrict__ d1,
                const int* __restrict__ dflag)
{
    const void* s = blockIdx.z ? s1 : s0;
    short* d = blockIdx.z ? d1 : d0;
    const size_t i = ((size_t)blockIdx.x * 256 + threadIdx.x) * 8;
    short8 o;
    if (*dflag) {
        const float4 f0 = ((const float4*)((const float*)s + i))[0];
        const float4 f1 = ((const float4*)((const float*)s + i))[1];
        o[0] = f2bf(f0.x); o[1] = f2bf(f0.y); o[2] = f2bf(f0.z); o[3] = f2bf(f0.w);
        o[4] = f2bf(f1.x); o[5] = f2bf(f1.y); o[6] = f2bf(f1.z); o[7] = f2bf(f1.w);
    } else {
        o = *(const short8*)((const short*)s + i);
    }
    *(short8*)(d + i) = o;
}

// Batched weight transpose: 4 matrices [R,C] -> bf16 [C,R], selected by blockIdx.z.
struct TP4 {
    const void* s[4];
    short* d[4];
};
__global__ __launch_bounds__(256)
void transpose4_k(TP4 p, int R, int C, const int* __restrict__ dflag)
{
    __shared__ short T[64][72];
    const int tid = threadIdx.x;
    const int bC = blockIdx.x, bR = blockIdx.y;
    const void* src = p.s[blockIdx.z];
    short* dst = p.d[blockIdx.z];
    const bool f32 = (*dflag != 0);

    const int colg = (tid & 7) * 8;
    #pragma unroll
    for (int h = 0; h < 2; ++h) {
        const int row = (tid >> 3) + 32 * h;
        const size_t idx = (size_t)(bR * 64 + row) * (size_t)C + (size_t)(bC * 64 + colg);
        short e[8];
        if (f32) {
            const float4 f0 = ((const float4*)((const float*)src + idx))[0];
            const float4 f1 = ((const float4*)((const float*)src + idx))[1];
            e[0] = f2bf(f0.x); e[1] = f2bf(f0.y); e[2] = f2bf(f0.z); e[3] = f2bf(f0.w);
            e[4] = f2bf(f1.x); e[5] = f2bf(f1.y); e[6] = f2bf(f1.z); e[7] = f2bf(f1.w);
        } else {
            short8 s = *(const short8*)((const short*)src + idx);
            #pragma unroll
            for (int j = 0; j < 8; ++j) e[j] = s[j];
        }
        #pragma unroll
        for (int j = 0; j < 8; ++j) T[colg + j][row] = e[j];
    }
    __syncthreads();
    #pragma unroll
    for (int h = 0; h < 2; ++h) {
        const int orow = (tid >> 3) + 32 * h;
        const int ocolg = (tid & 7) * 8;
        const size_t idx = (size_t)(bC * 64 + orow) * (size_t)R + (size_t)(bR * 64 + ocolg);
        *(short8*)(dst + idx) = *(const short8*)&T[orow][ocolg];
    }
}

// ---------------- 64x64-tile GEMM, bf16 A [2048,1024] x bf16 Bt [1024,1024] ----------
// C = A@Bt^T + bias. Two independent jobs selectable via blockIdx.z (batching Q & K
// projections doubles grid -> 4 blocks/CU). All dims fixed: M=2048, N=K=lda=ldb=ldc=1024.
struct GJ { const short* A; const short* B; const void* bias; void* C; };

template<int OSRC>
__global__ __launch_bounds__(256)
void gemm64_bt_k(GJ j0, GJ j1, const int* __restrict__ dflag)
{
    __shared__ __align__(16) short As[64][40];
    __shared__ __align__(16) short Bs[64][40];

    const GJ j = blockIdx.z ? j1 : j0;
    const int rtf = *dflag;

    const int tid  = threadIdx.x;
    const int bN   = blockIdx.x, bM = blockIdx.y;
    const int lane = tid & 63, wave = tid >> 6;
    const int wm   = (wave >> 1) * 32;
    const int wn   = (wave & 1) * 32;
    const int quad = lane >> 4, r16 = lane & 15;

    floatx4 acc[2][2];
    #pragma unroll
    for (int i = 0; i < 2; ++i)
        #pragma unroll
        for (int jj = 0; jj < 2; ++jj)
            acc[i][jj] = (floatx4){0.f, 0.f, 0.f, 0.f};

    const int ar = tid >> 2, ac = (tid & 3) * 8;

    for (int k0 = 0; k0 < 1024; k0 += 32) {
        *(short8*)&As[ar][ac] =
            *(const short8*)(j.A + (size_t)(bM * 64 + ar) * 1024 + (size_t)(k0 + ac));
        *(short8*)&Bs[ar][ac] =
            *(const short8*)(j.B + (size_t)(bN * 64 + ar) * 1024 + (size_t)(k0 + ac));
        __syncthreads();

        short8 a0 = *(const short8*)&As[wm + r16][quad * 8];
        short8 a1 = *(const short8*)&As[wm + 16 + r16][quad * 8];
        short8 b0 = *(const short8*)&Bs[wn + r16][quad * 8];
        short8 b1 = *(const short8*)&Bs[wn + 16 + r16][quad * 8];

        acc[0][0] = __builtin_amdgcn_mfma_f32_16x16x32_bf16(a0, b0, acc[0][0], 0, 0, 0);
        acc[0][1] = __builtin_amdgcn_mfma_f32_16x16x32_bf16(a0, b1, acc[0][1], 0, 0, 0);
        acc[1][0] = __builtin_amdgcn_mfma_f32_16x16x32_bf16(a1, b0, acc[1][0], 0, 0, 0);
        acc[1][1] = __builtin_amdgcn_mfma_f32_16x16x32_bf16(a1, b1, acc[1][1], 0, 0, 0);
        __syncthreads();
    }

    const bool of32 = (OSRC == SRC_F32) || (OSRC == SRC_RT && rtf);
    #pragma unroll
    for (int jj = 0; jj < 2; ++jj) {
        const int gc = bN * 64 + wn + jj * 16 + r16;
        const float bb = rtf ? ((const float*)j.bias)[gc]
                             : bf2f(((const unsigned short*)j.bias)[gc]);
        #pragma unroll
        for (int i = 0; i < 2; ++i) {
            #pragma unroll
            for (int rg = 0; rg < 4; ++rg) {
                const int gr = bM * 64 + wm + i * 16 + quad * 4 + rg;
                const float v = acc[i][jj][rg] + bb;
                if (of32)
                    ((float*)j.C)[(size_t)gr * 1024 + gc] = v;
                else
                    ((__hip_bfloat16*)j.C)[(size_t)gr * 1024 + gc] = __float2bfloat16(v);
            }
        }
    }
}

// ---------------- fused attention v4: 32 rows x 128-col K-tiles, 4 blocks/CU ----------
// Block = 32 Q-rows x 1 head, 256 threads, LDS 39680 B -> 4 blocks/CU (16 waves).
// Wave w: rows sp..sp+15 (sp=(w>>1)*16), col half hf=w&1 -> 4 col-tiles per 128-col
// K-tile (16 K-tiles). Per tile: MFMA scores, wave top-2 fold (m1,m2), atomicMax m1 to
// shared running max g1, barrier, ballot-compacted append of z >= thr with
// thr = max(g1-1, (g1+m2-1)/2) -- a proven lower bound on tau, so the keep-set is a
// superset of the sparsemax support. Michelot + ballot-compact + sparse PV per-wave.
__global__ __launch_bounds__(256, 4)
void attn_fused_k(const short* __restrict__ Qb, const short* __restrict__ Kb,
                  const short* __restrict__ Vb, short* __restrict__ Ob)
{
    __shared__ __align__(16) short sQ[32][72];
    __shared__ __align__(16) short sK[128][72];
    __shared__ unsigned cpk[32][CAP];
    __shared__ unsigned rmax[32];
    __shared__ int cnt[32];

    const int tid  = threadIdx.x;
    const int lane = tid & 63, wave = tid >> 6;
    const int quad = lane >> 4, r16 = lane & 15;
    const int row0 = blockIdx.x * 32;
    const int h    = blockIdx.y;
    const int sp   = (wave >> 1) * 16;
    const int hf   = wave & 1;
    const int myrow = sp + quad * 4;   // + rg

    if (tid < 32) { rmax[tid] = 0u; cnt[tid] = 0; }
    {
        const int r = tid >> 3, c = (tid & 7) * 8;
        *(short8*)&sQ[r][c] = *(const short8*)(Qb + (size_t)(row0 + r) * 1024 + h * 64 + c);
    }
    __syncthreads();

    const short8 qa0 = *(const short8*)&sQ[sp + r16][quad * 8];
    const short8 qa1 = *(const short8*)&sQ[sp + r16][32 + quad * 8];

    // wave-local running top-2 per owned row (distinct columns by construction)
    float rm1[4], rm2[4];
    #pragma unroll
    for (int rg = 0; rg < 4; ++rg) { rm1[rg] = -3.0e38f; rm2[rg] = -3.0e38f; }

    for (int s0 = 0; s0 < 2048; s0 += 128) {
        // stage 128x64 K-tile: 4 rows/thread
        #pragma unroll
        for (int i = 0; i < 4; ++i) {
            const int kr = (tid >> 3) + 32 * i, c = (tid & 7) * 8;
            *(short8*)&sK[kr][c] = *(const short8*)(Kb + (size_t)(s0 + kr) * 1024 + h * 64 + c);
        }
        __syncthreads();

        floatx4 acc[4];
        #pragma unroll
        for (int t = 0; t < 4; ++t) {
            const int ct = (hf + 2 * t) * 16;
            const short8 b0 = *(const short8*)&sK[ct + r16][quad * 8];
            const short8 b1 = *(const short8*)&sK[ct + r16][32 + quad * 8];
            floatx4 a = (floatx4){0.f, 0.f, 0.f, 0.f};
            a = __builtin_amdgcn_mfma_f32_16x16x32_bf16(qa0, b0, a, 0, 0, 0);
            a = __builtin_amdgcn_mfma_f32_16x16x32_bf16(qa1, b1, a, 0, 0, 0);
            #pragma unroll
            for (int rg = 0; rg < 4; ++rg) a[rg] *= 0.125f;
            acc[t] = a;
        }

        // per-row tile top-2 fold: lane-local 4 values, then 16-lane butterfly;
        // merge into running local top-2; post m1 to shared running max
        #pragma unroll
        for (int rg = 0; rg < 4; ++rg) {
            float m1ab = fmaxf(acc[0][rg], acc[1][rg]);
            float m2ab = fminf(acc[0][rg], acc[1][rg]);
            float m1cd = fmaxf(acc[2][rg], acc[3][rg]);
            float m2cd = fminf(acc[2][rg], acc[3][rg]);
            float m1 = fmaxf(m1ab, m1cd);
            float m2 = fmaxf(fminf(m1ab, m1cd), (m1ab >= m1cd) ? m2ab : m2cd);
            #pragma unroll
            for (int off = 1; off < 16; off <<= 1) {
                const float o1 = __shfl_xor(m1, off, 64);
                const float o2 = __shfl_xor(m2, off, 64);
                const float n2 = fmaxf(fminf(m1, o1), (m1 >= o1) ? m2 : o2);
                m1 = fmaxf(m1, o1);
                m2 = n2;
            }
            const float n1 = fmaxf(rm1[rg], m1);
            rm2[rg] = fmaxf(fminf(rm1[rg], m1), (rm1[rg] >= m1) ? rm2[rg] : m2);
            rm1[rg] = n1;
            if (r16 == 0) atomicMax(&rmax[myrow + rg], fmap(m1));
        }
        __syncthreads();   // rmax complete for this tile; sK reads done

        // ballot-compacted append of candidates z >= thr (overlaps next staging safely)
        #pragma unroll
        for (int rg = 0; rg < 4; ++rg) {
            const int row = myrow + rg;
            const float g1 = funmap(rmax[row]);
            const float thr = fmaxf(g1 - 1.0f, 0.5f * (g1 + rm2[rg]) - 0.5f);
            #pragma unroll
            for (int t = 0; t < 4; ++t) {
                const float val = acc[t][rg];
                const bool keep = (val >= thr);
                const unsigned long long m = __ballot(keep);
                const unsigned qm = (unsigned)((m >> (quad * 16)) & 0xFFFFull);
                int base = 0;
                if (r16 == 0 && qm) base = atomicAdd(&cnt[row], __popc(qm));
                base = __shfl(base, quad * 16, 64);
                if (keep) {
                    const int p = base + __popc(qm & ((1u << r16) - 1u));
                    if (p < CAP)
                        cpk[row][p] = ((unsigned)f2bfu(val) << 16)
                                    | (unsigned)(s0 + (hf + 2 * t) * 16 + r16);
                }
            }
        }
    }
    __syncthreads();   // all appends visible

    // ---- per-wave Michelot + PV on owned rows (wave w: rows w*8 .. w*8+7) ----
    const unsigned long long pre = (1ULL << lane) - 1ULL;
    for (int rr = 0; rr < 8; ++rr) {
        const int r = wave * 8 + rr;
        const int n = min(cnt[r], CAP);

        float v[2];
        unsigned short ii[2];
        #pragma unroll
        for (int i = 0; i < 2; ++i) {
            const int ix = lane + i * 64;
            if (ix < n) {
                const unsigned u = cpk[r][ix];
                v[i] = bf2f((unsigned short)(u >> 16));
                ii[i] = (unsigned short)(u & 0xFFFFu);
            } else { v[i] = -3.0e38f; ii[i] = 0; }
        }

        float tau = -3.0e38f, prevc = -1.0f;
        for (int it = 0; it < 24; ++it) {
            float s = 0.f, c = 0.f;
            #pragma unroll
            for (int i = 0; i < 2; ++i)
                if (v[i] > tau) { s += v[i]; c += 1.f; }
            #pragma unroll
            for (int off = 1; off < 64; off <<= 1) {
                s += __shfl_xor(s, off, 64);
                c += __shfl_xor(c, off, 64);
            }
            if (c == prevc) break;
            prevc = c;
            tau = (s - 1.0f) / c;
        }

        // ballot-compact support (p>0) to list front, p packed bf16
        int base = 0;
        #pragma unroll
        for (int i = 0; i < 2; ++i) {
            const float p = v[i] - tau;
            const unsigned long long m = __ballot(p > 0.f);
            const int w = base + __popcll(m & pre);
            if (p > 0.f) cpk[r][w] = ((unsigned)f2bfu(p) << 16) | (unsigned)ii[i];
            base += __popcll(m);
        }
        const int msup = base;

        // sparse PV gather: lane = output col; 4-deep independent loads
        const unsigned short* vb = (const unsigned short*)Vb + (size_t)h * 64 + lane;
        float o0 = 0.f, o1 = 0.f, o2 = 0.f, o3 = 0.f;
        int jj = 0;
        for (; jj + 4 <= msup; jj += 4) {
            const unsigned u0 = cpk[r][jj],     u1 = cpk[r][jj + 1];
            const unsigned u2 = cpk[r][jj + 2], u3 = cpk[r][jj + 3];
            o0 += bf2f((unsigned short)(u0 >> 16)) * bf2f(vb[(size_t)(u0 & 0xFFFFu) * 1024]);
            o1 += bf2f((unsigned short)(u1 >> 16)) * bf2f(vb[(size_t)(u1 & 0xFFFFu) * 1024]);
            o2 += bf2f((unsigned short)(u2 >> 16)) * bf2f(vb[(size_t)(u2 & 0xFFFFu) * 1024]);
            o3 += bf2f((unsigned short)(u3 >> 16)) * bf2f(vb[(size_t)(u3 & 0xFFFFu) * 1024]);
        }
        for (; jj < msup; ++jj) {
            const unsigned u0 = cpk[r][jj];
            o0 += bf2f((unsigned short)(u0 >> 16)) * bf2f(vb[(size_t)(u0 & 0xFFFFu) * 1024]);
        }
        Ob[((size_t)h * 2048 + row0 + r) * 64 + lane] = f2bf(o0 + o1 + o2 + o3);
    }
}

extern "C" void kernel_launch(void* const* d_in, const int* in_sizes, int n_in,
                              void* d_out, int out_size, void* d_ws, size_t ws_size,
                              hipStream_t stream)
{
    (void)in_sizes; (void)n_in; (void)out_size; (void)ws_size;

    const void* queries = d_in[0];
    const void* keys    = d_in[1];
    // d_in[2] ("values") unused by the reference.
    const void* Wq = d_in[3];
    const void* bq = d_in[4];
    const void* Wk = d_in[5];
    const void* bk = d_in[6];
    const void* Wv = d_in[7];
    const void* bv = d_in[8];
    const void* Wo = d_in[9];
    const void* bo = d_in[10];

    const int L = 2048, DM = 1024;
    const size_t LD = (size_t)L * DM;   // 2M elements

    int*   flag = (int*)d_ws;
    short* Qc  = (short*)((char*)d_ws + 256);  // bf16 queries      [2048,1024]
    short* Kc  = Qc + LD;                      // bf16 keys         [2048,1024]
    short* WqT = Kc + LD;                      // bf16 Wq^T         [1024,1024]
    short* WkT = WqT + (size_t)DM * DM;
    short* WvT = WkT + (size_t)DM * DM;
    short* WoT = WvT + (size_t)DM * DM;
    short* Qb  = WoT + (size_t)DM * DM;        // [2048,1024]
    short* Kb  = Qb + LD;
    short* Vb  = Kb + LD;
    short* Ob  = Vb + LD;                      // [H,2048,64] contiguous (== mixed view)

    dim3 blk(256);

    // 0) dtype detection
    detect_k<<<dim3(1), dim3(64), 0, stream>>>((const short*)queries, 4096, flag);

    // p1) convert queries/keys -> bf16
    convert2_k<<<dim3((unsigned)(LD / 2048), 1, 2), blk, 0, stream>>>(
        queries, keys, Qc, Kc, flag);

    // p2) transpose-convert the 4 weight matrices -> bf16 [N][K]
    {
        TP4 p;
        p.s[0] = Wq; p.s[1] = Wk; p.s[2] = Wv; p.s[3] = Wo;
        p.d[0] = WqT; p.d[1] = WkT; p.d[2] = WvT; p.d[3] = WoT;
        transpose4_k<<<dim3(DM / 64, DM / 64, 4), blk, 0, stream>>>(p, DM, DM, flag);
    }

    // 1) Qb & Kb projections batched (1024 blocks = 4/CU)
    {
        GJ jq{(const short*)Qc, WqT, bq, Qb};
        GJ jk{(const short*)Kc, WkT, bk, Kb};
        gemm64_bt_k<SRC_BF16><<<dim3(DM / 64, L / 64, 2), blk, 0, stream>>>(jq, jk, flag);
    }
    // 2) Vb = Kb @ WvT + bv   (reference quirk: V from key projection)
    {
        GJ jv{(const short*)Kb, WvT, bv, Vb};
        gemm64_bt_k<SRC_BF16><<<dim3(DM / 64, L / 64, 1), blk, 0, stream>>>(jv, jv, flag);
    }

    // 3) fused attention (scores never reach HBM)
    attn_fused_k<<<dim3(L / 32, 16), blk, 0, stream>>>(Qb, Kb, Vb, Ob);

    // 4) out = Ob(viewed [2048,1024]) @ WoT + bo -> d_out (dtype per flag)
    {
        GJ jo{(const short*)Ob, WoT, bo, d_out};
        gemm64_bt_k<SRC_RT><<<dim3(DM / 64, L / 64, 1), blk, 0, stream>>>(jo, jo, flag);
    }
}

// Round 2
// 266.446 us; speedup vs baseline: 1.0407x; 1.0196x over previous
//
#include <hip/hip_runtime.h>
#include <hip/hip_bf16.h>

// Hopfield sparsemax attention, MI355X gfx950.
// B=1, L=S=2048, D_MODEL=1024, H=16, DK=64. Inputs fp32 (runtime-detected), output per flag.
//
// Round-11 (attn: barrier-free, full-residency rewrite):
//   - 16 Q-rows/block, 4 waves each own all 16 rows x one column quarter.
//     Grid 2048 blocks = 8/CU; LDS 12.4 KB; __launch_bounds__(256,8) -> 32 waves/CU target.
//   - NO K/Q LDS staging: K per head = 256 KB (L2-resident); MFMA B-fragments loaded
//     straight from global. Main loop has ZERO barriers (was 2/tile).
//   - rmax shared via barrier-free LDS atomicMax (monotone; any read is a valid lower
//     bound; own wave's rm1 folded in). thr = max(g1-1,(g1+rm2)/2-1/2) <= tau proof:
//     subset top-2 <= global top-2 pairwise, and (G1+G2-1)/2 <= tau unconditionally.
//   - head->XCD pinning: h = (bid&7) + 8*(slot&1) so each XCD's L2 holds 2 heads
//     (512 KB K + 512 KB V of 4 MB).
//   - CAP 128->192 (4 quarter-waves append with wave-local m2; more headroom).
//   Rest of pipeline unchanged (convert, transpose4, 64x64 gemm, final projection).

typedef __attribute__((ext_vector_type(8))) short short8;
typedef __attribute__((ext_vector_type(4))) float floatx4;

#define SRC_BF16 0
#define SRC_F32  1
#define SRC_RT   2
#define CAP 192

__device__ __forceinline__ short f2bf(float f) {
    __hip_bfloat16 h = __float2bfloat16(f);
    return *reinterpret_cast<const short*>(&h);
}
__device__ __forceinline__ unsigned short f2bfu(float f) {
    __hip_bfloat16 h = __float2bfloat16(f);
    return *reinterpret_cast<const unsigned short*>(&h);
}
__device__ __forceinline__ float bf2f(unsigned short u) {
    return __uint_as_float(((unsigned)u) << 16);
}
// monotone float->uint map (order-preserving for all finite floats)
__device__ __forceinline__ unsigned fmap(float f) {
    unsigned u = __float_as_uint(f);
    return (u & 0x80000000u) ? ~u : (u | 0x80000000u);
}
__device__ __forceinline__ float funmap(unsigned u) {
    return (u & 0x80000000u) ? __uint_as_float(u ^ 0x80000000u) : __uint_as_float(~u);
}

// Detect input dtype: decode first n shorts as bf16; fp32-read-as-bf16 almost surely
// yields |x|>1e10 / inf / NaN. One 64-thread block.
__global__ void detect_k(const short* __restrict__ q, int n, int* __restrict__ flag)
{
    const int tid = threadIdx.x;
    int bad = 0;
    for (int i = tid; i < n; i += 64) {
        float f = bf2f((unsigned short)q[i]);
        if (!(fabsf(f) < 1e10f)) bad = 1;
    }
    unsigned long long m = __ballot(bad != 0);
    if (tid == 0) *flag = (m != 0ULL) ? 1 : 0;
}

// Flat convert (fp32|bf16 per flag) -> bf16. z selects one of two sources.
__global__ __launch_bounds__(256)
void convert2_k(const void* __restrict__ s0, const void* __restrict__ s1,
                short* __restrict__ d0, short* __restrict__ d1,
                const int* __restrict__ dflag)
{
    const void* s = blockIdx.z ? s1 : s0;
    short* d = blockIdx.z ? d1 : d0;
    const size_t i = ((size_t)blockIdx.x * 256 + threadIdx.x) * 8;
    short8 o;
    if (*dflag) {
        const float4 f0 = ((const float4*)((const float*)s + i))[0];
        const float4 f1 = ((const float4*)((const float*)s + i))[1];
        o[0] = f2bf(f0.x); o[1] = f2bf(f0.y); o[2] = f2bf(f0.z); o[3] = f2bf(f0.w);
        o[4] = f2bf(f1.x); o[5] = f2bf(f1.y); o[6] = f2bf(f1.z); o[7] = f2bf(f1.w);
    } else {
        o = *(const short8*)((const short*)s + i);
    }
    *(short8*)(d + i) = o;
}

// Batched weight transpose: 4 matrices [R,C] -> bf16 [C,R], selected by blockIdx.z.
struct TP4 {
    const void* s[4];
    short* d[4];
};
__global__ __launch_bounds__(256)
void transpose4_k(TP4 p, int R, int C, const int* __restrict__ dflag)
{
    __shared__ short T[64][72];
    const int tid = threadIdx.x;
    const int bC = blockIdx.x, bR = blockIdx.y;
    const void* src = p.s[blockIdx.z];
    short* dst = p.d[blockIdx.z];
    const bool f32 = (*dflag != 0);

    const int colg = (tid & 7) * 8;
    #pragma unroll
    for (int h = 0; h < 2; ++h) {
        const int row = (tid >> 3) + 32 * h;
        const size_t idx = (size_t)(bR * 64 + row) * (size_t)C + (size_t)(bC * 64 + colg);
        short e[8];
        if (f32) {
            const float4 f0 = ((const float4*)((const float*)src + idx))[0];
            const float4 f1 = ((const float4*)((const float*)src + idx))[1];
            e[0] = f2bf(f0.x); e[1] = f2bf(f0.y); e[2] = f2bf(f0.z); e[3] = f2bf(f0.w);
            e[4] = f2bf(f1.x); e[5] = f2bf(f1.y); e[6] = f2bf(f1.z); e[7] = f2bf(f1.w);
        } else {
            short8 s = *(const short8*)((const short*)src + idx);
            #pragma unroll
            for (int j = 0; j < 8; ++j) e[j] = s[j];
        }
        #pragma unroll
        for (int j = 0; j < 8; ++j) T[colg + j][row] = e[j];
    }
    __syncthreads();
    #pragma unroll
    for (int h = 0; h < 2; ++h) {
        const int orow = (tid >> 3) + 32 * h;
        const int ocolg = (tid & 7) * 8;
        const size_t idx = (size_t)(bC * 64 + orow) * (size_t)R + (size_t)(bR * 64 + ocolg);
        *(short8*)(dst + idx) = *(const short8*)&T[orow][ocolg];
    }
}

// ---------------- 64x64-tile GEMM, bf16 A [2048,1024] x bf16 Bt [1024,1024] ----------
// C = A@Bt^T + bias. Two independent jobs selectable via blockIdx.z (batching Q & K
// projections doubles grid -> 4 blocks/CU). All dims fixed: M=2048, N=K=lda=ldb=ldc=1024.
struct GJ { const short* A; const short* B; const void* bias; void* C; };

template<int OSRC>
__global__ __launch_bounds__(256)
void gemm64_bt_k(GJ j0, GJ j1, const int* __restrict__ dflag)
{
    __shared__ __align__(16) short As[64][40];
    __shared__ __align__(16) short Bs[64][40];

    const GJ j = blockIdx.z ? j1 : j0;
    const int rtf = *dflag;

    const int tid  = threadIdx.x;
    const int bN   = blockIdx.x, bM = blockIdx.y;
    const int lane = tid & 63, wave = tid >> 6;
    const int wm   = (wave >> 1) * 32;
    const int wn   = (wave & 1) * 32;
    const int quad = lane >> 4, r16 = lane & 15;

    floatx4 acc[2][2];
    #pragma unroll
    for (int i = 0; i < 2; ++i)
        #pragma unroll
        for (int jj = 0; jj < 2; ++jj)
            acc[i][jj] = (floatx4){0.f, 0.f, 0.f, 0.f};

    const int ar = tid >> 2, ac = (tid & 3) * 8;

    for (int k0 = 0; k0 < 1024; k0 += 32) {
        *(short8*)&As[ar][ac] =
            *(const short8*)(j.A + (size_t)(bM * 64 + ar) * 1024 + (size_t)(k0 + ac));
        *(short8*)&Bs[ar][ac] =
            *(const short8*)(j.B + (size_t)(bN * 64 + ar) * 1024 + (size_t)(k0 + ac));
        __syncthreads();

        short8 a0 = *(const short8*)&As[wm + r16][quad * 8];
        short8 a1 = *(const short8*)&As[wm + 16 + r16][quad * 8];
        short8 b0 = *(const short8*)&Bs[wn + r16][quad * 8];
        short8 b1 = *(const short8*)&Bs[wn + 16 + r16][quad * 8];

        acc[0][0] = __builtin_amdgcn_mfma_f32_16x16x32_bf16(a0, b0, acc[0][0], 0, 0, 0);
        acc[0][1] = __builtin_amdgcn_mfma_f32_16x16x32_bf16(a0, b1, acc[0][1], 0, 0, 0);
        acc[1][0] = __builtin_amdgcn_mfma_f32_16x16x32_bf16(a1, b0, acc[1][0], 0, 0, 0);
        acc[1][1] = __builtin_amdgcn_mfma_f32_16x16x32_bf16(a1, b1, acc[1][1], 0, 0, 0);
        __syncthreads();
    }

    const bool of32 = (OSRC == SRC_F32) || (OSRC == SRC_RT && rtf);
    #pragma unroll
    for (int jj = 0; jj < 2; ++jj) {
        const int gc = bN * 64 + wn + jj * 16 + r16;
        const float bb = rtf ? ((const float*)j.bias)[gc]
                             : bf2f(((const unsigned short*)j.bias)[gc]);
        #pragma unroll
        for (int i = 0; i < 2; ++i) {
            #pragma unroll
            for (int rg = 0; rg < 4; ++rg) {
                const int gr = bM * 64 + wm + i * 16 + quad * 4 + rg;
                const float v = acc[i][jj][rg] + bb;
                if (of32)
                    ((float*)j.C)[(size_t)gr * 1024 + gc] = v;
                else
                    ((__hip_bfloat16*)j.C)[(size_t)gr * 1024 + gc] = __float2bfloat16(v);
            }
        }
    }
}

// ---------------- fused attention v5: barrier-free, 16 rows/block, 8 blocks/CU -------
// Block = 16 Q-rows x 1 head, 256 threads (4 waves). Wave w owns ALL 16 rows x column
// quarter w: per 256-col step, col-tiles ct=(w+4t)*16, t=0..3 (acc[4]). K fragments are
// loaded DIRECTLY from global (K/head = 256 KB, L2-resident; b0+b1 consume full 128B
// lines). No LDS staging, no barriers in the main loop. Per tile: MFMA scores, wave
// top-2 fold, barrier-free atomicMax to shared rmax, append candidates z >= thr packed
// (bf16(z)<<16)|kidx with thr = max(g1-1,(g1+m2-1)/2) (valid tau lower bound; see
// header). Michelot + ballot-compact + sparse PV gather per-wave on owned rows.
__global__ __launch_bounds__(256, 8)
void attn_fused_k(const short* __restrict__ Qb, const short* __restrict__ Kb,
                  const short* __restrict__ Vb, short* __restrict__ Ob)
{
    __shared__ unsigned cpk[16][CAP];
    __shared__ unsigned rmax[16];
    __shared__ int cnt[16];

    const int tid  = threadIdx.x;
    const int lane = tid & 63, wave = tid >> 6;
    const int quad = lane >> 4, r16 = lane & 15;

    // head->XCD pinning: blocks with bid%8==x carry heads x and x+8 (round-robin
    // block->XCD assumed; wrong mapping only costs L2 locality, never correctness).
    const int bid  = blockIdx.x;
    const int slot = bid >> 3;
    const int h    = (slot & 1) * 8 + (bid & 7);
    const int row0 = (slot >> 1) * 16;

    if (tid < 16) { rmax[tid] = fmap(-3.0e38f); cnt[tid] = 0; }
    __syncthreads();

    // Q fragment, direct from global (all 4 waves read the same 2 KB; L1-hot)
    const short* qp = Qb + (size_t)(row0 + r16) * 1024 + h * 64 + quad * 8;
    const short8 qa0 = *(const short8*)qp;
    const short8 qa1 = *(const short8*)(qp + 32);

    const int myrow = quad * 4;          // + rg
    const short* kp0 = Kb + (size_t)(wave * 16 + r16) * 1024 + h * 64 + quad * 8;

    // wave-local running top-2 per owned row (over this wave's column quarter)
    float rm1[4], rm2[4];
    #pragma unroll
    for (int rg = 0; rg < 4; ++rg) { rm1[rg] = -3.0e38f; rm2[rg] = -3.0e38f; }

    for (int s0 = 0; s0 < 2048; s0 += 256) {
        floatx4 acc[4];
        #pragma unroll
        for (int t = 0; t < 4; ++t) {
            const short* kp = kp0 + (size_t)(s0 + t * 64) * 1024;
            const short8 b0 = *(const short8*)kp;
            const short8 b1 = *(const short8*)(kp + 32);
            floatx4 a = (floatx4){0.f, 0.f, 0.f, 0.f};
            a = __builtin_amdgcn_mfma_f32_16x16x32_bf16(qa0, b0, a, 0, 0, 0);
            a = __builtin_amdgcn_mfma_f32_16x16x32_bf16(qa1, b1, a, 0, 0, 0);
            #pragma unroll
            for (int rg = 0; rg < 4; ++rg) a[rg] *= 0.125f;
            acc[t] = a;
        }

        // per-row tile top-2 fold (lane-local 4 vals, 16-lane butterfly), merge into
        // running top-2, post m1 to shared rmax (barrier-free; monotone)
        #pragma unroll
        for (int rg = 0; rg < 4; ++rg) {
            float m1ab = fmaxf(acc[0][rg], acc[1][rg]);
            float m2ab = fminf(acc[0][rg], acc[1][rg]);
            float m1cd = fmaxf(acc[2][rg], acc[3][rg]);
            float m2cd = fminf(acc[2][rg], acc[3][rg]);
            float m1 = fmaxf(m1ab, m1cd);
            float m2 = fmaxf(fminf(m1ab, m1cd), (m1ab >= m1cd) ? m2ab : m2cd);
            #pragma unroll
            for (int off = 1; off < 16; off <<= 1) {
                const float o1 = __shfl_xor(m1, off, 64);
                const float o2 = __shfl_xor(m2, off, 64);
                const float n2 = fmaxf(fminf(m1, o1), (m1 >= o1) ? m2 : o2);
                m1 = fmaxf(m1, o1);
                m2 = n2;
            }
            const float n1 = fmaxf(rm1[rg], m1);
            rm2[rg] = fmaxf(fminf(rm1[rg], m1), (rm1[rg] >= m1) ? rm2[rg] : m2);
            rm1[rg] = n1;
            if (r16 == 0) atomicMax(&rmax[myrow + rg], fmap(m1));
        }

        // ballot-compacted append of candidates z >= thr (no barrier; any rmax read is
        // a valid lower bound of the final max, and own rm1 is folded in)
        #pragma unroll
        for (int rg = 0; rg < 4; ++rg) {
            const int row = myrow + rg;
            const float g1 = fmaxf(funmap(rmax[row]), rm1[rg]);
            const float thr = fmaxf(g1 - 1.0f, 0.5f * (g1 + rm2[rg]) - 0.5f);
            #pragma unroll
            for (int t = 0; t < 4; ++t) {
                const float val = acc[t][rg];
                const bool keep = (val >= thr);
                const unsigned long long m = __ballot(keep);
                const unsigned qm = (unsigned)((m >> (quad * 16)) & 0xFFFFull);
                int base = 0;
                if (r16 == 0 && qm) base = atomicAdd(&cnt[row], __popc(qm));
                base = __shfl(base, quad * 16, 64);
                if (keep) {
                    const int p = base + __popc(qm & ((1u << r16) - 1u));
                    if (p < CAP)
                        cpk[row][p] = ((unsigned)f2bfu(val) << 16)
                                    | (unsigned)(s0 + wave * 16 + t * 64 + r16);
                }
            }
        }
    }
    __syncthreads();   // all appends visible

    // ---- per-wave Michelot + PV on owned rows (wave w: rows w*4 .. w*4+3) ----
    const unsigned long long pre = (1ULL << lane) - 1ULL;
    for (int rr = 0; rr < 4; ++rr) {
        const int r = wave * 4 + rr;
        const int n = min(cnt[r], CAP);

        float v[3];
        unsigned short ii[3];
        #pragma unroll
        for (int i = 0; i < 3; ++i) {
            const int ix = lane + i * 64;
            if (ix < n) {
                const unsigned u = cpk[r][ix];
                v[i] = bf2f((unsigned short)(u >> 16));
                ii[i] = (unsigned short)(u & 0xFFFFu);
            } else { v[i] = -3.0e38f; ii[i] = 0; }
        }

        float tau = -3.0e38f, prevc = -1.0f;
        for (int it = 0; it < 24; ++it) {
            float s = 0.f, c = 0.f;
            #pragma unroll
            for (int i = 0; i < 3; ++i)
                if (v[i] > tau) { s += v[i]; c += 1.f; }
            #pragma unroll
            for (int off = 1; off < 64; off <<= 1) {
                s += __shfl_xor(s, off, 64);
                c += __shfl_xor(c, off, 64);
            }
            if (c == prevc) break;
            prevc = c;
            tau = (s - 1.0f) / c;
        }

        // ballot-compact support (p>0) to list front, p packed bf16
        int base = 0;
        #pragma unroll
        for (int i = 0; i < 3; ++i) {
            const float p = v[i] - tau;
            const unsigned long long m = __ballot(p > 0.f);
            const int w = base + __popcll(m & pre);
            if (p > 0.f) cpk[r][w] = ((unsigned)f2bfu(p) << 16) | (unsigned)ii[i];
            base += __popcll(m);
        }
        const int msup = base;

        // sparse PV gather: lane = output col; 4-deep independent loads
        const unsigned short* vb = (const unsigned short*)Vb + (size_t)h * 64 + lane;
        float o0 = 0.f, o1 = 0.f, o2 = 0.f, o3 = 0.f;
        int jj = 0;
        for (; jj + 4 <= msup; jj += 4) {
            const unsigned u0 = cpk[r][jj],     u1 = cpk[r][jj + 1];
            const unsigned u2 = cpk[r][jj + 2], u3 = cpk[r][jj + 3];
            o0 += bf2f((unsigned short)(u0 >> 16)) * bf2f(vb[(size_t)(u0 & 0xFFFFu) * 1024]);
            o1 += bf2f((unsigned short)(u1 >> 16)) * bf2f(vb[(size_t)(u1 & 0xFFFFu) * 1024]);
            o2 += bf2f((unsigned short)(u2 >> 16)) * bf2f(vb[(size_t)(u2 & 0xFFFFu) * 1024]);
            o3 += bf2f((unsigned short)(u3 >> 16)) * bf2f(vb[(size_t)(u3 & 0xFFFFu) * 1024]);
        }
        for (; jj < msup; ++jj) {
            const unsigned u0 = cpk[r][jj];
            o0 += bf2f((unsigned short)(u0 >> 16)) * bf2f(vb[(size_t)(u0 & 0xFFFFu) * 1024]);
        }
        Ob[((size_t)h * 2048 + row0 + r) * 64 + lane] = f2bf(o0 + o1 + o2 + o3);
    }
}

extern "C" void kernel_launch(void* const* d_in, const int* in_sizes, int n_in,
                              void* d_out, int out_size, void* d_ws, size_t ws_size,
                              hipStream_t stream)
{
    (void)in_sizes; (void)n_in; (void)out_size; (void)ws_size;

    const void* queries = d_in[0];
    const void* keys    = d_in[1];
    // d_in[2] ("values") unused by the reference.
    const void* Wq = d_in[3];
    const void* bq = d_in[4];
    const void* Wk = d_in[5];
    const void* bk = d_in[6];
    const void* Wv = d_in[7];
    const void* bv = d_in[8];
    const void* Wo = d_in[9];
    const void* bo = d_in[10];

    const int L = 2048, DM = 1024;
    const size_t LD = (size_t)L * DM;   // 2M elements

    int*   flag = (int*)d_ws;
    short* Qc  = (short*)((char*)d_ws + 256);  // bf16 queries      [2048,1024]
    short* Kc  = Qc + LD;                      // bf16 keys         [2048,1024]
    short* WqT = Kc + LD;                      // bf16 Wq^T         [1024,1024]
    short* WkT = WqT + (size_t)DM * DM;
    short* WvT = WkT + (size_t)DM * DM;
    short* WoT = WvT + (size_t)DM * DM;
    short* Qb  = WoT + (size_t)DM * DM;        // [2048,1024]
    short* Kb  = Qb + LD;
    short* Vb  = Kb + LD;
    short* Ob  = Vb + LD;                      // [H,2048,64] contiguous (== mixed view)

    dim3 blk(256);

    // 0) dtype detection
    detect_k<<<dim3(1), dim3(64), 0, stream>>>((const short*)queries, 4096, flag);

    // p1) convert queries/keys -> bf16
    convert2_k<<<dim3((unsigned)(LD / 2048), 1, 2), blk, 0, stream>>>(
        queries, keys, Qc, Kc, flag);

    // p2) transpose-convert the 4 weight matrices -> bf16 [N][K]
    {
        TP4 p;
        p.s[0] = Wq; p.s[1] = Wk; p.s[2] = Wv; p.s[3] = Wo;
        p.d[0] = WqT; p.d[1] = WkT; p.d[2] = WvT; p.d[3] = WoT;
        transpose4_k<<<dim3(DM / 64, DM / 64, 4), blk, 0, stream>>>(p, DM, DM, flag);
    }

    // 1) Qb & Kb projections batched (1024 blocks = 4/CU)
    {
        GJ jq{(const short*)Qc, WqT, bq, Qb};
        GJ jk{(const short*)Kc, WkT, bk, Kb};
        gemm64_bt_k<SRC_BF16><<<dim3(DM / 64, L / 64, 2), blk, 0, stream>>>(jq, jk, flag);
    }
    // 2) Vb = Kb @ WvT + bv   (reference quirk: V from key projection)
    {
        GJ jv{(const short*)Kb, WvT, bv, Vb};
        gemm64_bt_k<SRC_BF16><<<dim3(DM / 64, L / 64, 1), blk, 0, stream>>>(jv, jv, flag);
    }

    // 3) fused attention (scores never reach HBM; barrier-free main loop)
    attn_fused_k<<<dim3((L / 16) * 16), blk, 0, stream>>>(Qb, Kb, Vb, Ob);

    // 4) out = Ob(viewed [2048,1024]) @ WoT + bo -> d_out (dtype per flag)
    {
        GJ jo{(const short*)Ob, WoT, bo, d_out};
        gemm64_bt_k<SRC_RT><<<dim3(DM / 64, L / 64, 1), blk, 0, stream>>>(jo, jo, flag);
    }
}